// Round 1
// baseline (364.307 us; speedup 1.0000x reference)
//
#include <hip/hip_runtime.h>

#define BINS    64
#define RWIN    5                 // window radius in bins (tail < 5e-8 relative)
#define GUARD   RWIN
#define HB      (BINS + 2*GUARD)  // 74 padded bins -> no bounds checks
#define NR      8                 // LDS replicas (indexed by lane&7)
#define CHUNKS  64                // blocks per channel-image
#define NPIX    (512*512)         // pixels per channel
#define PPB     (NPIX / CHUNKS)   // 4096 pixels per block
#define THREADS 256
#define NCH     12                // 4*3 channel-images per input

__global__ __launch_bounds__(THREADS) void hist_kernel(
    const float* __restrict__ pred, const float* __restrict__ target,
    float* __restrict__ ghist /* [2][NCH][BINS] */)
{
    __shared__ float lh[HB * NR];
    const int tid = threadIdx.x;
    for (int i = tid; i < HB * NR; i += THREADS) lh[i] = 0.0f;
    __syncthreads();

    const int chunk = blockIdx.x;
    const int ch    = blockIdx.y;
    const int z     = blockIdx.z;
    const float* src = (z == 0 ? pred : target)
                     + (size_t)ch * NPIX + (size_t)chunk * PPB;
    const float4* src4 = (const float4*)src;
    const int r = tid & (NR - 1);

    // C_k = exp(-k*k/2)
    const float C1 = 0.60653065971e0f;
    const float C2 = 0.13533528324e0f;
    const float C3 = 1.11089965382e-2f;
    const float C4 = 3.35462627903e-4f;
    const float C5 = 3.72665317208e-6f;

    #pragma unroll
    for (int k = 0; k < PPB / 4 / THREADS; ++k) {
        float4 v = src4[(size_t)k * THREADS + tid];
        float xv[4] = {v.x, v.y, v.z, v.w};
        #pragma unroll
        for (int e = 0; e < 4; ++e) {
            float xs = xv[e] * 64.0f;
            float fi = floorf(xs);
            int   i0 = (int)fi;
            float d  = xs - fi - 0.5f;          // in [-0.5, 0.5]
            float t0 = __expf(-0.5f * d * d);   // e^{-d^2/2}
            float g  = __expf(d);               // e^{d}
            float gi = __expf(-d);              // e^{-d}
            float* base = &lh[(i0 + GUARD) * NR + r];
            atomicAdd(base, t0);
            float pp = g, pm = gi, s;
            s = t0 * C1;
            atomicAdd(base + 1 * NR, s * pp);
            atomicAdd(base - 1 * NR, s * pm);
            pp *= g; pm *= gi; s = t0 * C2;
            atomicAdd(base + 2 * NR, s * pp);
            atomicAdd(base - 2 * NR, s * pm);
            pp *= g; pm *= gi; s = t0 * C3;
            atomicAdd(base + 3 * NR, s * pp);
            atomicAdd(base - 3 * NR, s * pm);
            pp *= g; pm *= gi; s = t0 * C4;
            atomicAdd(base + 4 * NR, s * pp);
            atomicAdd(base - 4 * NR, s * pm);
            pp *= g; pm *= gi; s = t0 * C5;
            atomicAdd(base + 5 * NR, s * pp);
            atomicAdd(base - 5 * NR, s * pm);
        }
    }
    __syncthreads();

    if (tid < BINS) {
        float sum = 0.0f;
        #pragma unroll
        for (int q = 0; q < NR; ++q) sum += lh[(tid + GUARD) * NR + q];
        atomicAdd(&ghist[((size_t)z * NCH + ch) * BINS + tid], sum);
    }
}

__global__ void finalize_kernel(const float* __restrict__ ghist,
                                float* __restrict__ out)
{
    const int lane = threadIdx.x;   // 64 threads, lane == bin
    float acc = 0.0f;
    for (int ch = 0; ch < NCH; ++ch) {
        float cp = ghist[ch * BINS + lane];
        float ct = ghist[NCH * BINS + ch * BINS + lane];
        // inclusive prefix sum across 64 lanes
        #pragma unroll
        for (int off = 1; off < 64; off <<= 1) {
            float a = __shfl_up(cp, off, 64);
            float b = __shfl_up(ct, off, 64);
            if (lane >= off) { cp += a; ct += b; }
        }
        float sp = __shfl(cp, 63, 64);
        float st = __shfl(ct, 63, 64);
        float diff = fabsf(cp / (sp + 1e-8f) - ct / (st + 1e-8f));
        #pragma unroll
        for (int off = 32; off; off >>= 1)
            diff += __shfl_xor(diff, off, 64);
        acc += diff;   // every lane holds the same channel total now
    }
    if (lane == 0) out[0] = acc / (float)(NCH * BINS);
}

extern "C" void kernel_launch(void* const* d_in, const int* in_sizes, int n_in,
                              void* d_out, int out_size, void* d_ws, size_t ws_size,
                              hipStream_t stream)
{
    const float* pred   = (const float*)d_in[0];
    const float* target = (const float*)d_in[1];
    float* ghist = (float*)d_ws;   // 2*12*64 = 1536 floats

    hipMemsetAsync(ghist, 0, 2 * NCH * BINS * sizeof(float), stream);
    hist_kernel<<<dim3(CHUNKS, NCH, 2), THREADS, 0, stream>>>(pred, target, ghist);
    finalize_kernel<<<1, 64, 0, stream>>>(ghist, (float*)d_out);
}

// Round 2
// 363.248 us; speedup vs baseline: 1.0029x; 1.0029x over previous
//
#include <hip/hip_runtime.h>
#include <stdint.h>

#define BINS    64
#define RWIN    5                 // window radius in bins (tail < 5e-8 relative)
#define GUARD   RWIN
#define HB      (BINS + 2*GUARD)  // 74 padded bins -> no bounds checks
#define NR      16                // LDS replicas (indexed by lane&15)
#define CHUNKS  64                // blocks per channel-image
#define NPIX    (512*512)         // pixels per channel
#define PPB     (NPIX / CHUNKS)   // 4096 pixels per block
#define THREADS 256
#define NCH     12                // 4*3 channel-images per input

// Native LDS float add (no return): avoids hipcc's CAS-loop lowering of
// atomicAdd(float*) on LDS. addr is the LDS byte offset (low 32 bits of the
// generic pointer to a __shared__ object).
__device__ __forceinline__ void ds_fadd(uint32_t addr, float v) {
    asm volatile("ds_add_f32 %0, %1" :: "v"(addr), "v"(v) : "memory");
}

__global__ __launch_bounds__(THREADS) void hist_kernel(
    const float* __restrict__ pred, const float* __restrict__ target,
    float* __restrict__ ghist /* [2][NCH][BINS] */)
{
    __shared__ float lh[HB * NR];
    const int tid = threadIdx.x;
    for (int i = tid; i < HB * NR; i += THREADS) lh[i] = 0.0f;
    __syncthreads();

    const int chunk = blockIdx.x;
    const int ch    = blockIdx.y;
    const int z     = blockIdx.z;
    const float* src = (z == 0 ? pred : target)
                     + (size_t)ch * NPIX + (size_t)chunk * PPB;
    const float4* src4 = (const float4*)src;
    const int r = tid & (NR - 1);
    const uint32_t lbase = (uint32_t)(uintptr_t)(&lh[0]) + ((uint32_t)r << 2);

    // C_k = exp(-k*k/2)
    const float C1 = 0.60653065971e0f;
    const float C2 = 0.13533528324e0f;
    const float C3 = 1.11089965382e-2f;
    const float C4 = 3.35462627903e-4f;
    const float C5 = 3.72665317208e-6f;

    #pragma unroll
    for (int k = 0; k < PPB / 4 / THREADS; ++k) {
        float4 v = src4[(size_t)k * THREADS + tid];
        float xv[4] = {v.x, v.y, v.z, v.w};
        #pragma unroll
        for (int e = 0; e < 4; ++e) {
            float xs = xv[e] * 64.0f;
            float fi = floorf(xs);
            int   i0 = (int)fi;                 // 0..63
            float d  = xs - fi - 0.5f;          // in [-0.5, 0.5]
            float t0 = __expf(-0.5f * d * d);   // e^{-d^2/2}
            float g  = __expf(d);               // e^{d}
            float gi = __expf(-d);              // e^{-d}
            // bin b = i0 + j, padded row = b + GUARD; base row (j=-5) = i0.
            uint32_t a = lbase + ((uint32_t)i0 << 6);   // i0 * NR * 4
            float pp = g, pm = gi, s;
            ds_fadd(a + 5 * NR * 4, t0);                 // j = 0
            s = t0 * C1;
            ds_fadd(a + 6 * NR * 4, s * pp);             // j = +1
            ds_fadd(a + 4 * NR * 4, s * pm);             // j = -1
            pp *= g; pm *= gi; s = t0 * C2;
            ds_fadd(a + 7 * NR * 4, s * pp);
            ds_fadd(a + 3 * NR * 4, s * pm);
            pp *= g; pm *= gi; s = t0 * C3;
            ds_fadd(a + 8 * NR * 4, s * pp);
            ds_fadd(a + 2 * NR * 4, s * pm);
            pp *= g; pm *= gi; s = t0 * C4;
            ds_fadd(a + 9 * NR * 4, s * pp);
            ds_fadd(a + 1 * NR * 4, s * pm);
            pp *= g; pm *= gi; s = t0 * C5;
            ds_fadd(a + 10 * NR * 4, s * pp);
            ds_fadd(a + 0 * NR * 4, s * pm);
        }
    }
    // Our DS traffic is in inline asm -> drain explicitly before the barrier.
    asm volatile("s_waitcnt lgkmcnt(0)" ::: "memory");
    __syncthreads();

    if (tid < BINS) {
        float sum = 0.0f;
        #pragma unroll
        for (int q = 0; q < NR; ++q) sum += lh[(tid + GUARD) * NR + q];
        float* gp = &ghist[((size_t)z * NCH + ch) * BINS + tid];
        // Native global float atomic (no return) - avoids CAS loop.
        asm volatile("global_atomic_add_f32 %0, %1, off" :: "v"(gp), "v"(sum) : "memory");
    }
    asm volatile("s_waitcnt vmcnt(0)" ::: "memory");
}

__global__ void finalize_kernel(const float* __restrict__ ghist,
                                float* __restrict__ out)
{
    const int lane = threadIdx.x;   // 64 threads, lane == bin
    float acc = 0.0f;
    for (int ch = 0; ch < NCH; ++ch) {
        float cp = ghist[ch * BINS + lane];
        float ct = ghist[NCH * BINS + ch * BINS + lane];
        // inclusive prefix sum across 64 lanes
        #pragma unroll
        for (int off = 1; off < 64; off <<= 1) {
            float a = __shfl_up(cp, off, 64);
            float b = __shfl_up(ct, off, 64);
            if (lane >= off) { cp += a; ct += b; }
        }
        float sp = __shfl(cp, 63, 64);
        float st = __shfl(ct, 63, 64);
        float diff = fabsf(cp / (sp + 1e-8f) - ct / (st + 1e-8f));
        #pragma unroll
        for (int off = 32; off; off >>= 1)
            diff += __shfl_xor(diff, off, 64);
        acc += diff;   // every lane holds the same channel total now
    }
    if (lane == 0) out[0] = acc / (float)(NCH * BINS);
}

extern "C" void kernel_launch(void* const* d_in, const int* in_sizes, int n_in,
                              void* d_out, int out_size, void* d_ws, size_t ws_size,
                              hipStream_t stream)
{
    const float* pred   = (const float*)d_in[0];
    const float* target = (const float*)d_in[1];
    float* ghist = (float*)d_ws;   // 2*12*64 = 1536 floats

    hipMemsetAsync(ghist, 0, 2 * NCH * BINS * sizeof(float), stream);
    hist_kernel<<<dim3(CHUNKS, NCH, 2), THREADS, 0, stream>>>(pred, target, ghist);
    finalize_kernel<<<1, 64, 0, stream>>>(ghist, (float*)d_out);
}

// Round 3
// 47.312 us; speedup vs baseline: 7.7000x; 7.6776x over previous
//
#include <hip/hip_runtime.h>
#include <stdint.h>

#define BINS    64
#define PAIRS   36                // pair-rows P+m+2, P in 0..31, m in -2..2
#define STRIDE  74                // dwords per thread column (72 + 2 pad); gcd(74,32)=2
#define THREADS 128
#define CHUNKS  128               // blocks per channel-image
#define NPIX    (512*512)
#define PPB     (NPIX / CHUNKS)   // 2048 pixels per block
#define NCH     12                // 4*3 channel-images per input

__global__ __launch_bounds__(THREADS) void hist_kernel(
    const float* __restrict__ pred, const float* __restrict__ target,
    float* __restrict__ ghist /* [2][NCH][BINS] */)
{
    __shared__ float lh[THREADS * STRIDE];   // 37888 B
    const int tid = threadIdx.x;

    // zero own column (37 x ds_write_b64, 8B-aligned since STRIDE is even)
    float2* mycol = (float2*)&lh[tid * STRIDE];
    #pragma unroll
    for (int i = 0; i < STRIDE / 2; ++i) mycol[i] = make_float2(0.f, 0.f);
    __syncthreads();

    const int chunk = blockIdx.x;
    const int ch    = blockIdx.y;
    const int z     = blockIdx.z;
    const float* src = (z == 0 ? pred : target)
                     + (size_t)ch * NPIX + (size_t)chunk * PPB;
    const float4* src4 = (const float4*)src;

    // C_k = exp(-k*k/2)
    const float C1 = 0.60653065971e0f;
    const float C2 = 0.13533528324e0f;
    const float C3 = 1.11089965382e-2f;
    const float C4 = 3.35462627903e-4f;
    const float C5 = 3.72665317208e-6f;

    float2* base = (float2*)lh + tid * (STRIDE / 2);   // 37 float2 slots

    #pragma unroll
    for (int k = 0; k < PPB / 4 / THREADS; ++k) {
        float4 v = src4[(size_t)k * THREADS + tid];
        float xv[4] = {v.x, v.y, v.z, v.w};
        #pragma unroll
        for (int e = 0; e < 4; ++e) {
            float xs = xv[e] * 64.0f;            // [0, 64)
            float fp = floorf(xs * 0.5f);        // pair index P: 0..31
            int   P  = (int)fp;
            float d  = xs - 2.0f * fp - 0.5f;    // delta in [-0.5, 1.5)
            float t0 = __expf(-0.5f * d * d);
            float g  = __expf(d);
            float gi = __expf(-d);
            // w_k = t0 * g^k * C_|k|, k = -4..5 ; coverage radius >= 4.5 bins
            float pm, pp;
            pm = gi;            float wm1 = t0 * C1 * pm;
            pm *= gi;           float wm2 = t0 * C2 * pm;
            pm *= gi;           float wm3 = t0 * C3 * pm;
            pm *= gi;           float wm4 = t0 * C4 * pm;
            pp = g;             float w1  = t0 * C1 * pp;
            pp *= g;            float w2  = t0 * C2 * pp;
            pp *= g;            float w3  = t0 * C3 * pp;
            pp *= g;            float w4  = t0 * C4 * pp;
            pp *= g;            float w5  = t0 * C5 * pp;
            // slots: base[P + (m+2)] covers bins 2(P+m), 2(P+m)+1
            float2* c = base + P;
            float2 a0 = c[0]; a0.x += wm4; a0.y += wm3; c[0] = a0;
            float2 a1 = c[1]; a1.x += wm2; a1.y += wm1; c[1] = a1;
            float2 a2 = c[2]; a2.x += t0;  a2.y += w1;  c[2] = a2;
            float2 a3 = c[3]; a3.x += w2;  a3.y += w3;  c[3] = a3;
            float2 a4 = c[4]; a4.x += w4;  a4.y += w5;  c[4] = a4;
        }
    }
    __syncthreads();

    // reduce: bin b lives at dword (b + 4) of every column
    const int bin = tid & 63;
    const int h   = tid >> 6;           // which half of the 128 columns
    float s = 0.0f;
    #pragma unroll
    for (int i = 0; i < 64; ++i)
        s += lh[(h * 64 + i) * STRIDE + bin + 4];
    lh[tid * STRIDE + 72] = s;          // pad dword as scratch
    __syncthreads();

    if (tid < 64) {
        float tot = lh[tid * STRIDE + 72] + lh[(tid + 64) * STRIDE + 72];
        float* gp = &ghist[((size_t)z * NCH + ch) * BINS + tid];
        asm volatile("global_atomic_add_f32 %0, %1, off" :: "v"(gp), "v"(tot) : "memory");
    }
    asm volatile("s_waitcnt vmcnt(0)" ::: "memory");
}

__global__ void finalize_kernel(const float* __restrict__ ghist,
                                float* __restrict__ out)
{
    const int lane = threadIdx.x;   // 64 threads, lane == bin
    float acc = 0.0f;
    for (int ch = 0; ch < NCH; ++ch) {
        float cp = ghist[ch * BINS + lane];
        float ct = ghist[NCH * BINS + ch * BINS + lane];
        #pragma unroll
        for (int off = 1; off < 64; off <<= 1) {
            float a = __shfl_up(cp, off, 64);
            float b = __shfl_up(ct, off, 64);
            if (lane >= off) { cp += a; ct += b; }
        }
        float sp = __shfl(cp, 63, 64);
        float st = __shfl(ct, 63, 64);
        float diff = fabsf(cp / (sp + 1e-8f) - ct / (st + 1e-8f));
        #pragma unroll
        for (int off = 32; off; off >>= 1)
            diff += __shfl_xor(diff, off, 64);
        acc += diff;
    }
    if (lane == 0) out[0] = acc / (float)(NCH * BINS);
}

extern "C" void kernel_launch(void* const* d_in, const int* in_sizes, int n_in,
                              void* d_out, int out_size, void* d_ws, size_t ws_size,
                              hipStream_t stream)
{
    const float* pred   = (const float*)d_in[0];
    const float* target = (const float*)d_in[1];
    float* ghist = (float*)d_ws;   // 2*12*64 = 1536 floats

    hipMemsetAsync(ghist, 0, 2 * NCH * BINS * sizeof(float), stream);
    hist_kernel<<<dim3(CHUNKS, NCH, 2), THREADS, 0, stream>>>(pred, target, ghist);
    finalize_kernel<<<1, 64, 0, stream>>>(ghist, (float*)d_out);
}

// Round 4
// 46.663 us; speedup vs baseline: 7.8071x; 1.0139x over previous
//
#include <hip/hip_runtime.h>
#include <stdint.h>

#define BINS    64
#define STRIDE  74                // dwords per thread column (72 + 2 pad); gcd(74,32)=2
#define THREADS 128
#define CHUNKS  64                // blocks per channel-image
#define NPIX    (512*512)
#define PPB     (NPIX / CHUNKS)   // 4096 pixels per block
#define NCH     12                // 4*3 channel-images per input

__global__ __launch_bounds__(THREADS) void hist_kernel(
    const float* __restrict__ pred, const float* __restrict__ target,
    float* __restrict__ part /* [2][NCH][CHUNKS][BINS] */)
{
    __shared__ float lh[THREADS * STRIDE];   // 37888 B
    const int tid = threadIdx.x;

    // zero own column (37 x ds_write_b64)
    float2* mycol = (float2*)&lh[tid * STRIDE];
    #pragma unroll
    for (int i = 0; i < STRIDE / 2; ++i) mycol[i] = make_float2(0.f, 0.f);
    __syncthreads();

    const int chunk = blockIdx.x;
    const int ch    = blockIdx.y;
    const int z     = blockIdx.z;
    const float* src = (z == 0 ? pred : target)
                     + (size_t)ch * NPIX + (size_t)chunk * PPB;
    const float4* src4 = (const float4*)src;

    // C_k = exp(-k*k/2)
    const float C1 = 0.60653065971e0f;
    const float C2 = 0.13533528324e0f;
    const float C3 = 1.11089965382e-2f;
    const float C4 = 3.35462627903e-4f;
    const float C5 = 3.72665317208e-6f;

    float2* base = (float2*)lh + tid * (STRIDE / 2);   // 37 float2 slots

    #pragma unroll 4
    for (int k = 0; k < PPB / 4 / THREADS; ++k) {
        float4 v = src4[(size_t)k * THREADS + tid];
        float xv[4] = {v.x, v.y, v.z, v.w};
        #pragma unroll
        for (int e = 0; e < 4; ++e) {
            float xs = xv[e] * 64.0f;            // [0, 64)
            float fp = floorf(xs * 0.5f);        // pair index P: 0..31
            int   P  = (int)fp;
            float d  = xs - 2.0f * fp - 0.5f;    // delta in [-0.5, 1.5)
            float t0 = __expf(-0.5f * d * d);
            float g  = __expf(d);
            float gi = __expf(-d);
            // w_k = t0 * g^k * C_|k|, k = -4..5 ; coverage radius >= 4.5 bins
            float pm, pp;
            pm = gi;            float wm1 = t0 * C1 * pm;
            pm *= gi;           float wm2 = t0 * C2 * pm;
            pm *= gi;           float wm3 = t0 * C3 * pm;
            pm *= gi;           float wm4 = t0 * C4 * pm;
            pp = g;             float w1  = t0 * C1 * pp;
            pp *= g;            float w2  = t0 * C2 * pp;
            pp *= g;            float w3  = t0 * C3 * pp;
            pp *= g;            float w4  = t0 * C4 * pp;
            pp *= g;            float w5  = t0 * C5 * pp;
            // slots: base[P + (m+2)] covers bins 2(P+m), 2(P+m)+1
            float2* c = base + P;
            float2 a0 = c[0]; a0.x += wm4; a0.y += wm3; c[0] = a0;
            float2 a1 = c[1]; a1.x += wm2; a1.y += wm1; c[1] = a1;
            float2 a2 = c[2]; a2.x += t0;  a2.y += w1;  c[2] = a2;
            float2 a3 = c[3]; a3.x += w2;  a3.y += w3;  c[3] = a3;
            float2 a4 = c[4]; a4.x += w4;  a4.y += w5;  c[4] = a4;
        }
    }
    __syncthreads();

    // reduce: bin b lives at dword (b + 4) of every column
    const int bin = tid & 63;
    const int h   = tid >> 6;           // which half of the 128 columns
    float s = 0.0f;
    #pragma unroll
    for (int i = 0; i < 64; ++i)
        s += lh[(h * 64 + i) * STRIDE + bin + 4];
    lh[tid * STRIDE + 72] = s;          // pad dword as scratch
    __syncthreads();

    if (tid < 64) {
        float tot = lh[tid * STRIDE + 72] + lh[(tid + 64) * STRIDE + 72];
        // plain store to this block's private partial slot -- no atomics,
        // no zero-init required, deterministic across graph replays.
        part[(((size_t)z * NCH + ch) * CHUNKS + chunk) * BINS + tid] = tot;
    }
}

__global__ __launch_bounds__(256) void finalize_kernel(
    const float* __restrict__ part, float* __restrict__ out)
{
    __shared__ float wsum[4];
    const int tid  = threadIdx.x;
    const int lane = tid & 63;          // lane == bin
    const int w    = tid >> 6;          // wave id 0..3, handles 3 channels
    float acc = 0.0f;
    for (int c = w * 3; c < w * 3 + 3; ++c) {
        float cp = 0.0f, ct = 0.0f;
        #pragma unroll 8
        for (int i = 0; i < CHUNKS; ++i)
            cp += part[((size_t)(0 * NCH + c) * CHUNKS + i) * BINS + lane];
        #pragma unroll 8
        for (int i = 0; i < CHUNKS; ++i)
            ct += part[((size_t)(1 * NCH + c) * CHUNKS + i) * BINS + lane];
        // inclusive prefix sum across 64 lanes
        #pragma unroll
        for (int off = 1; off < 64; off <<= 1) {
            float a = __shfl_up(cp, off, 64);
            float b = __shfl_up(ct, off, 64);
            if (lane >= off) { cp += a; ct += b; }
        }
        float sp = __shfl(cp, 63, 64);
        float st = __shfl(ct, 63, 64);
        float diff = fabsf(cp / (sp + 1e-8f) - ct / (st + 1e-8f));
        #pragma unroll
        for (int off = 32; off; off >>= 1)
            diff += __shfl_xor(diff, off, 64);
        acc += diff;                    // all lanes now hold the channel total
    }
    if (lane == 0) wsum[w] = acc;
    __syncthreads();
    if (tid == 0)
        out[0] = (wsum[0] + wsum[1] + wsum[2] + wsum[3]) / (float)(NCH * BINS);
}

extern "C" void kernel_launch(void* const* d_in, const int* in_sizes, int n_in,
                              void* d_out, int out_size, void* d_ws, size_t ws_size,
                              hipStream_t stream)
{
    const float* pred   = (const float*)d_in[0];
    const float* target = (const float*)d_in[1];
    float* part = (float*)d_ws;   // 2*12*64*64 floats = 393 KB

    hist_kernel<<<dim3(CHUNKS, NCH, 2), THREADS, 0, stream>>>(pred, target, part);
    finalize_kernel<<<1, 256, 0, stream>>>(part, (float*)d_out);
}

// Round 5
// 37.052 us; speedup vs baseline: 9.8322x; 1.2594x over previous
//
#include <hip/hip_runtime.h>
#include <stdint.h>

#define BINS    64
#define NF4     19                // float4 slots per thread column (bins -4..71)
#define STRIDE  76                // dwords per column = 4*NF4 (16B aligned)
#define THREADS 128
#define CHUNKS  64                // blocks per channel-image
#define NPIX    (512*512)
#define PPB     (NPIX / CHUNKS)   // 4096 pixels per block
#define ITERS   (PPB / 4 / THREADS)   // 8 float4 iterations per thread
#define NCH     12                // 4*3 channel-images per input

__global__ __launch_bounds__(THREADS) void hist_kernel(
    const float* __restrict__ pred, const float* __restrict__ target,
    float* __restrict__ part /* [2][NCH][CHUNKS][BINS] */)
{
    __shared__ float4 lh4[THREADS * NF4];   // 38912 B
    const int tid = threadIdx.x;

    float4* base = &lh4[tid * NF4];
    #pragma unroll
    for (int i = 0; i < NF4; ++i) base[i] = make_float4(0.f, 0.f, 0.f, 0.f);
    __syncthreads();

    const int chunk = blockIdx.x;
    const int ch    = blockIdx.y;
    const int z     = blockIdx.z;
    const float* src = (z == 0 ? pred : target)
                     + (size_t)ch * NPIX + (size_t)chunk * PPB;
    const float4* src4 = (const float4*)src;

    // C_k = exp(-k*k/2)
    const float C1 = 0.60653065971e0f;
    const float C2 = 0.13533528324e0f;
    const float C3 = 1.11089965382e-2f;
    const float C4 = 3.35462627903e-4f;
    const float C5 = 3.72665317208e-6f;
    const float C6 = 1.52299797447e-8f;

    float4 v = src4[tid];
    #pragma unroll
    for (int k = 0; k < ITERS; ++k) {
        float4 vn = (k + 1 < ITERS) ? src4[(size_t)(k + 1) * THREADS + tid]
                                    : make_float4(0.f, 0.f, 0.f, 0.f);
        float xv[4] = {v.x, v.y, v.z, v.w};
        #pragma unroll
        for (int e = 0; e < 4; ++e) {
            float xs = xv[e] * 64.0f;            // [0, 64)
            float fq = floorf(xs * 0.25f);       // quad index Q: 0..15
            int   Q  = (int)fq;
            float d0 = xs - 4.0f * fq - 1.5f;    // in [-1.5, 2.5)
            float t0 = __expf(-0.5f * d0 * d0);
            float g  = __expf(d0);
            float gi = __expf(-d0);
            // w for bin 4Q+o (o=-4..7): k=o-1 in -5..6, w = t0*C_|k|*g^k
            float t1 = t0 * C1, t2 = t0 * C2, t3 = t0 * C3;
            float t4 = t0 * C4, t5 = t0 * C5, t6 = t0 * C6;
            float g2 = g * g,   g3 = g2 * g,  g4 = g2 * g2;
            float g5 = g3 * g2, g6 = g3 * g3;
            float h2 = gi * gi, h3 = h2 * gi, h4 = h2 * h2, h5 = h3 * h2;
            float4* c = base + Q;
            float4 a0 = c[0], a1 = c[1], a2 = c[2];
            a0.x += t5 * h5; a0.y += t4 * h4; a0.z += t3 * h3; a0.w += t2 * h2;
            a1.x += t1 * gi; a1.y += t0;      a1.z += t1 * g;  a1.w += t2 * g2;
            a2.x += t3 * g3; a2.y += t4 * g4; a2.z += t5 * g5; a2.w += t6 * g6;
            c[0] = a0; c[1] = a1; c[2] = a2;
        }
        v = vn;
    }
    __syncthreads();

    // bin b lives at dword (b + 4) of each 76-dword column
    const float* lhf = (const float*)lh4;
    float* lhw = (float*)lh4;
    const int bin = tid & 63;
    const int h   = tid >> 6;
    float s = 0.0f;
    #pragma unroll 8
    for (int i = 0; i < 64; ++i)
        s += lhf[(h * 64 + i) * STRIDE + bin + 4];
    __syncthreads();                 // reads done before scratch overwrite
    lhw[tid * STRIDE + 72] = s;      // dword 72 (bin 68) never receives deposits
    __syncthreads();

    if (tid < 64) {
        float tot = lhf[tid * STRIDE + 72] + lhf[(tid + 64) * STRIDE + 72];
        part[(((size_t)z * NCH + ch) * CHUNKS + chunk) * BINS + tid] = tot;
    }
}

// Fold chunk partials: 24 blocks (one per channel-image), 64 threads (bin).
__global__ __launch_bounds__(64) void reduce_kernel(
    const float* __restrict__ part, float* __restrict__ chist /* [24][BINS] */)
{
    const int ci  = blockIdx.x;
    const int bin = threadIdx.x;
    float s = 0.0f;
    #pragma unroll 16
    for (int i = 0; i < CHUNKS; ++i)
        s += part[((size_t)ci * CHUNKS + i) * BINS + bin];
    chist[ci * BINS + bin] = s;
}

__global__ __launch_bounds__(256) void finalize_kernel(
    const float* __restrict__ chist, float* __restrict__ out)
{
    __shared__ float wsum[4];
    const int tid  = threadIdx.x;
    const int lane = tid & 63;          // lane == bin
    const int w    = tid >> 6;          // wave id 0..3, handles 3 channels
    float acc = 0.0f;
    for (int c = w * 3; c < w * 3 + 3; ++c) {
        float cp = chist[c * BINS + lane];
        float ct = chist[(NCH + c) * BINS + lane];
        #pragma unroll
        for (int off = 1; off < 64; off <<= 1) {
            float a = __shfl_up(cp, off, 64);
            float b = __shfl_up(ct, off, 64);
            if (lane >= off) { cp += a; ct += b; }
        }
        float sp = __shfl(cp, 63, 64);
        float st = __shfl(ct, 63, 64);
        float diff = fabsf(cp / (sp + 1e-8f) - ct / (st + 1e-8f));
        #pragma unroll
        for (int off = 32; off; off >>= 1)
            diff += __shfl_xor(diff, off, 64);
        acc += diff;
    }
    if (lane == 0) wsum[w] = acc;
    __syncthreads();
    if (tid == 0)
        out[0] = (wsum[0] + wsum[1] + wsum[2] + wsum[3]) / (float)(NCH * BINS);
}

extern "C" void kernel_launch(void* const* d_in, const int* in_sizes, int n_in,
                              void* d_out, int out_size, void* d_ws, size_t ws_size,
                              hipStream_t stream)
{
    const float* pred   = (const float*)d_in[0];
    const float* target = (const float*)d_in[1];
    float* part  = (float*)d_ws;                  // 2*12*64*64 floats
    float* chist = part + 2 * NCH * CHUNKS * BINS; // 24*64 floats

    hist_kernel<<<dim3(CHUNKS, NCH, 2), THREADS, 0, stream>>>(pred, target, part);
    reduce_kernel<<<2 * NCH, 64, 0, stream>>>(part, chist);
    finalize_kernel<<<1, 256, 0, stream>>>(chist, (float*)d_out);
}